// Round 3
// baseline (418.608 us; speedup 1.0000x reference)
//
#include <hip/hip_runtime.h>
#include <hip/hip_bf16.h>

// NNP species-MLP energy sum.  Strategy: counting-sort atoms by species so
// each wave is species-uniform, then bf16 MFMA (16x16x32) per 16-atom tile.
// Memory floor: 256MB desc + 4MB species ~= 42us @ 6.3TB/s.

#define NATOMS 500000
#define NSPEC  4
#define DIN    128
#define DH1    32
#define DH2    32

#define IDX_CAP 500064            // NATOMS + 64 (room for 4x align-16 pads)
#define T_MAX   (IDX_CAP / 16)    // 31254 tiles

// ---- workspace layout (bytes) ----
#define OFF_COUNTS 0              // int[4]
#define OFF_CURS   16             // int[4]
#define OFF_BASES  32             // int[5]
#define OFF_IDX    256            // int[IDX_CAP]
#define OFF_FRAG   2000640        // 256 + IDX_CAP*4 = 2000512, rounded to 128
#define SPEC_STRIDE 11840         // per-species frag block
// within a species block:
//   W0 frags : 8 frags (kt0..3 x jt0..1) * 64 lanes * 16B   @ 0      (8192B)
//   W1 frags : 2 frags * 64 * 16B                           @ 8192   (2048B)
//   b0 frag  : 2 * 64 * f32                                 @ 10240  (512B)
//   b1 frag  : 2 * 64 * f32                                 @ 10752  (512B)
//   W2 frag  : 2 * 64 * f32                                 @ 11264  (512B)

typedef __bf16 bf16x8 __attribute__((ext_vector_type(8)));
typedef float  f32x4  __attribute__((ext_vector_type(4)));

__device__ __forceinline__ float fast_tanh(float x) {
    // tanh(x) = 1 - 2/(exp(2x)+1); exp(2x) = 2^(x*2.885390...)
    float e = exp2f(x * 2.8853900817779268f);
    return 1.0f - 2.0f / (e + 1.0f);
}

// ---------- K0: zero counters + output ----------
__global__ void k0_init(char* ws, float* out) {
    int t = threadIdx.x;
    if (t < 4) ((int*)(ws + OFF_COUNTS))[t] = 0;
    if (t == 0) out[0] = 0.0f;
}

// ---------- K1: species histogram ----------
__global__ void k1_hist(const int* __restrict__ species, char* ws) {
    __shared__ int h[NSPEC];
    int t = threadIdx.x;
    if (t < NSPEC) h[t] = 0;
    __syncthreads();
    int i = blockIdx.x * blockDim.x + t;
    if (i < NATOMS) {
        int s = species[i];
        atomicAdd(&h[s], 1);
    }
    __syncthreads();
    if (t < NSPEC) atomicAdd((int*)(ws + OFF_COUNTS) + t, h[t]);
}

// ---------- K2: bases/cursors/pads + weight pre-fragmentation ----------
__global__ void k2_prep(const float* __restrict__ W0, const float* __restrict__ b0,
                        const float* __restrict__ W1, const float* __restrict__ b1,
                        const float* __restrict__ W2, char* ws) {
    int tid = threadIdx.x;
    int* counts = (int*)(ws + OFF_COUNTS);
    int* curs   = (int*)(ws + OFF_CURS);
    int* bases  = (int*)(ws + OFF_BASES);
    int* idx    = (int*)(ws + OFF_IDX);

    if (tid == 0) {
        int b = 0;
        bases[0] = 0;
        for (int s = 0; s < NSPEC; s++) {
            int c = counts[s];
            int a = (c + 15) & ~15;          // align segment to whole tiles
            curs[s] = b;                     // scatter cursor starts at base
            for (int p = b + c; p < b + a; p++) idx[p] = -1;  // pad slots
            b += a;
            bases[s + 1] = b;
        }
        for (int p = b; p < IDX_CAP; p++) idx[p] = -1;        // trailing pads
    }

    // 256 threads = 4 species x 64 lanes: build MFMA B-fragments.
    int s = tid >> 6, l = tid & 63;
    int kg = l >> 4, lo = l & 15;
    char* fb = ws + OFF_FRAG + (size_t)s * SPEC_STRIDE;

    // W0: B[k][j], k = kt*32 + kg*8 + e, j = jt*16 + lo
    for (int kt = 0; kt < 4; kt++) {
        for (int jt = 0; jt < 2; jt++) {
            bf16x8 v;
            for (int e = 0; e < 8; e++) {
                int k = kt * 32 + kg * 8 + e;
                int j = jt * 16 + lo;
                v[e] = (__bf16)W0[(s * DIN + k) * DH1 + j];
            }
            *(bf16x8*)(fb + (kt * 2 + jt) * 1024 + l * 16) = v;
        }
    }
    // W1: B[k][j], k = kg*8 + e (K=32 in one mfma), j = jt*16 + lo
    for (int jt = 0; jt < 2; jt++) {
        bf16x8 v;
        for (int e = 0; e < 8; e++) {
            int k = kg * 8 + e;
            int j = jt * 16 + lo;
            v[e] = (__bf16)W1[(s * DH1 + k) * DH2 + j];
        }
        *(bf16x8*)(fb + 8192 + jt * 1024 + l * 16) = v;
    }
    for (int jt = 0; jt < 2; jt++) {
        *(float*)(fb + 10240 + (jt * 64 + l) * 4) = b0[s * DH1 + jt * 16 + lo];
        *(float*)(fb + 10752 + (jt * 64 + l) * 4) = b1[s * DH2 + jt * 16 + lo];
        *(float*)(fb + 11264 + (jt * 64 + l) * 4) = W2[s * DH2 + jt * 16 + lo];
    }
}

// ---------- K3: scatter atom indices into species segments ----------
__global__ void k3_scatter(const int* __restrict__ species, char* ws) {
    __shared__ int h[NSPEC];
    __shared__ int base[NSPEC];
    int t = threadIdx.x;
    if (t < NSPEC) h[t] = 0;
    __syncthreads();
    int i = blockIdx.x * blockDim.x + t;
    int s = 0, r = 0;
    bool ok = (i < NATOMS);
    if (ok) {
        s = species[i];
        r = atomicAdd(&h[s], 1);
    }
    __syncthreads();
    if (t < NSPEC) base[t] = atomicAdd((int*)(ws + OFF_CURS) + t, h[t]);
    __syncthreads();
    if (ok) ((int*)(ws + OFF_IDX))[base[s] + r] = i;
}

// ---------- K4: main MLP+reduce kernel ----------
__global__ __launch_bounds__(256) void k4_main(const float* __restrict__ desc,
                                               const float* __restrict__ b2,
                                               const char* __restrict__ ws,
                                               float* __restrict__ out) {
    // per-wave 16x32 bf16 relayout buffer (layer0 C-layout -> layer1 A-layout)
    __shared__ alignas(16) __bf16 h1buf[4][16][32];

    const int* bases = (const int*)(ws + OFF_BASES);
    const int* idx   = (const int*)(ws + OFF_IDX);

    int tid = threadIdx.x;
    int l   = tid & 63;
    int w   = tid >> 6;
    int lo  = l & 15;     // A row / C col index
    int kg  = l >> 4;     // k-group (A) / row-group (C)

    int gw = blockIdx.x * 4 + w;
    int nw = gridDim.x * 4;
    int chunk = (T_MAX + nw - 1) / nw;
    int t0 = gw * chunk;
    int t1 = t0 + chunk; if (t1 > T_MAX) t1 = T_MAX;
    if (t0 >= t1) return;                      // no block-wide syncs below

    int B1 = bases[1], B2 = bases[2], B3 = bases[3];

    int scur = -1;
    bf16x8 w0f[4][2], w1f[2];
    float b0f[2], b1f[2], w2f[2], b2v = 0.0f;
    float esum = 0.0f;

    for (int t = t0; t < t1; t++) {
        int p0 = t * 16;
        int s = (p0 >= B3) ? 3 : (p0 >= B2) ? 2 : (p0 >= B1) ? 1 : 0;
        if (s != scur) {
            const char* fb = ws + OFF_FRAG + (size_t)s * SPEC_STRIDE;
#pragma unroll
            for (int kt = 0; kt < 4; kt++) {
                w0f[kt][0] = *(const bf16x8*)(fb + (kt * 2 + 0) * 1024 + l * 16);
                w0f[kt][1] = *(const bf16x8*)(fb + (kt * 2 + 1) * 1024 + l * 16);
            }
            w1f[0] = *(const bf16x8*)(fb + 8192 + l * 16);
            w1f[1] = *(const bf16x8*)(fb + 8192 + 1024 + l * 16);
            b0f[0] = *(const float*)(fb + 10240 + l * 4);
            b0f[1] = *(const float*)(fb + 10240 + (64 + l) * 4);
            b1f[0] = *(const float*)(fb + 10752 + l * 4);
            b1f[1] = *(const float*)(fb + 10752 + (64 + l) * 4);
            w2f[0] = *(const float*)(fb + 11264 + l * 4);
            w2f[1] = *(const float*)(fb + 11264 + (64 + l) * 4);
            b2v = b2[s];
            scur = s;
        }

        int idxv = idx[p0 + lo];
        int atom = idxv < 0 ? 0 : idxv;        // clamp; masked at reduction
        const float* dp = desc + (size_t)atom * DIN + kg * 8;

        f32x4 acc0 = {0.f, 0.f, 0.f, 0.f}, acc1 = {0.f, 0.f, 0.f, 0.f};
#pragma unroll
        for (int kt = 0; kt < 4; kt++) {
            float4 x = *(const float4*)(dp + kt * 32);
            float4 y = *(const float4*)(dp + kt * 32 + 4);
            bf16x8 a;
            a[0] = (__bf16)x.x; a[1] = (__bf16)x.y; a[2] = (__bf16)x.z; a[3] = (__bf16)x.w;
            a[4] = (__bf16)y.x; a[5] = (__bf16)y.y; a[6] = (__bf16)y.z; a[7] = (__bf16)y.w;
            acc0 = __builtin_amdgcn_mfma_f32_16x16x32_bf16(a, w0f[kt][0], acc0, 0, 0, 0);
            acc1 = __builtin_amdgcn_mfma_f32_16x16x32_bf16(a, w0f[kt][1], acc1, 0, 0, 0);
        }

        // layer0 epilogue -> LDS with 16B-chunk XOR swizzle (bank-conflict-free)
#pragma unroll
        for (int jt = 0; jt < 2; jt++) {
            float bb = b0f[jt];
#pragma unroll
            for (int r = 0; r < 4; r++) {
                float v = fast_tanh((jt ? acc1[r] : acc0[r]) + bb);
                int roww = kg * 4 + r;
                int col  = jt * 16 + lo;
                int sw   = (col >> 3) ^ (roww & 3) ^ (roww >> 2);
                h1buf[w][roww][sw * 8 + (col & 7)] = (__bf16)v;
            }
        }
        // read layer1 A-frag: row = lo, chunk = kg (same-wave DS ops are in-order)
        int swr = kg ^ (lo & 3) ^ ((lo >> 2) & 3);
        bf16x8 ha = *(bf16x8*)&h1buf[w][lo][swr * 8];

        f32x4 c10 = {0.f, 0.f, 0.f, 0.f}, c11 = {0.f, 0.f, 0.f, 0.f};
        c10 = __builtin_amdgcn_mfma_f32_16x16x32_bf16(ha, w1f[0], c10, 0, 0, 0);
        c11 = __builtin_amdgcn_mfma_f32_16x16x32_bf16(ha, w1f[1], c11, 0, 0, 0);

        // layer2: per-lane partial over its 2 columns, then reduce over 16 cols
        float p[4];
#pragma unroll
        for (int r = 0; r < 4; r++) {
            float h20 = fast_tanh(c10[r] + b1f[0]);
            float h21 = fast_tanh(c11[r] + b1f[1]);
            p[r] = h20 * w2f[0] + h21 * w2f[1];
        }
#pragma unroll
        for (int r = 0; r < 4; r++) {
            p[r] += __shfl_xor(p[r], 1);
            p[r] += __shfl_xor(p[r], 2);
            p[r] += __shfl_xor(p[r], 4);
            p[r] += __shfl_xor(p[r], 8);
        }

        unsigned long long bal = __ballot(idxv >= 0);  // bit (l&15) = row valid
        float te = 0.0f;
#pragma unroll
        for (int r = 0; r < 4; r++) {
            int roww = kg * 4 + r;
            if ((bal >> roww) & 1ULL) te += p[r] + b2v;
        }
        te += __shfl_xor(te, 16);
        te += __shfl_xor(te, 32);
        esum += te;
    }
    if (l == 0) atomicAdd(out, esum);
}

extern "C" void kernel_launch(void* const* d_in, const int* in_sizes, int n_in,
                              void* d_out, int out_size, void* d_ws, size_t ws_size,
                              hipStream_t stream) {
    const float* desc    = (const float*)d_in[0];
    const int*   species = (const int*)d_in[1];
    const float* W0      = (const float*)d_in[2];
    const float* b0      = (const float*)d_in[3];
    const float* W1      = (const float*)d_in[4];
    const float* b1      = (const float*)d_in[5];
    const float* W2      = (const float*)d_in[6];
    const float* b2      = (const float*)d_in[7];
    char*  ws  = (char*)d_ws;
    float* out = (float*)d_out;

    int nb = (NATOMS + 1023) / 1024;   // 489

    k0_init<<<1, 64, 0, stream>>>(ws, out);
    k1_hist<<<nb, 1024, 0, stream>>>(species, ws);
    k2_prep<<<1, 256, 0, stream>>>(W0, b0, W1, b1, W2, ws);
    k3_scatter<<<nb, 1024, 0, stream>>>(species, ws);
    k4_main<<<1024, 256, 0, stream>>>(desc, b2, ws, out);
}

// Round 5
// 390.937 us; speedup vs baseline: 1.0708x; 1.0708x over previous
//
#include <hip/hip_runtime.h>
#include <hip/hip_bf16.h>

// NNP species-MLP energy sum.  Counting-sort atoms by species; each wave is
// species-uniform and runs bf16 MFMA (16x16x32) on 16-atom tiles.
// R4: k4 latency attack — idx preload + one-tile-ahead register prefetch
// (static ping-pong dA/dB), deferred cross-lane reduction (ballot-masked
// per-lane accumulation; 6 shfl once per wave), strided balanced tiling.

#define NATOMS 500000
#define NSPEC  4
#define DIN    128
#define DH1    32
#define DH2    32

#define IDX_CAP 500064            // NATOMS rounded up (4x align-16 pads)
#define T_MAX   (IDX_CAP / 16)    // 31254 tiles

#define K4_BLOCKS 768             // 3 blocks/CU at ~140 VGPR occupancy
#define K4_WAVES  (K4_BLOCKS * 4) // 3072
#define CHUNK     11              // ceil(T_MAX / K4_WAVES)

// ---- workspace layout (bytes) ----
#define OFF_COUNTS 0              // int[4]
#define OFF_CURS   16             // int[4]
#define OFF_BASES  32             // int[5]
#define OFF_IDX    256            // int[IDX_CAP]
#define OFF_FRAG   2000640        // frag blocks, 128-aligned
#define SPEC_STRIDE 11840         // per-species frag block

typedef __bf16 bf16x8 __attribute__((ext_vector_type(8)));
typedef float  f32x4  __attribute__((ext_vector_type(4)));

__device__ __forceinline__ float fast_tanh(float x) {
    float e = exp2f(x * 2.8853900817779268f);
    return 1.0f - 2.0f / (e + 1.0f);
}

// ---------- K0: zero counters + output ----------
__global__ void k0_init(char* ws, float* out) {
    int t = threadIdx.x;
    if (t < 4) ((int*)(ws + OFF_COUNTS))[t] = 0;
    if (t == 0) out[0] = 0.0f;
}

// ---------- K1: species histogram ----------
__global__ void k1_hist(const int* __restrict__ species, char* ws) {
    __shared__ int h[NSPEC];
    int t = threadIdx.x;
    if (t < NSPEC) h[t] = 0;
    __syncthreads();
    int i = blockIdx.x * blockDim.x + t;
    if (i < NATOMS) atomicAdd(&h[species[i]], 1);
    __syncthreads();
    if (t < NSPEC) atomicAdd((int*)(ws + OFF_COUNTS) + t, h[t]);
}

// ---------- K2: bases/cursors/pads + weight pre-fragmentation ----------
__global__ void k2_prep(const float* __restrict__ W0, const float* __restrict__ b0,
                        const float* __restrict__ W1, const float* __restrict__ b1,
                        const float* __restrict__ W2, char* ws) {
    int tid = threadIdx.x;
    int* counts = (int*)(ws + OFF_COUNTS);
    int* curs   = (int*)(ws + OFF_CURS);
    int* bases  = (int*)(ws + OFF_BASES);
    int* idx    = (int*)(ws + OFF_IDX);

    if (tid == 0) {
        int b = 0;
        bases[0] = 0;
        for (int s = 0; s < NSPEC; s++) {
            int c = counts[s];
            int a = (c + 15) & ~15;
            curs[s] = b;
            for (int p = b + c; p < b + a; p++) idx[p] = -1;
            b += a;
            bases[s + 1] = b;
        }
        for (int p = b; p < IDX_CAP; p++) idx[p] = -1;
    }

    int s = tid >> 6, l = tid & 63;
    int kg = l >> 4, lo = l & 15;
    char* fb = ws + OFF_FRAG + (size_t)s * SPEC_STRIDE;

    for (int kt = 0; kt < 4; kt++) {
        for (int jt = 0; jt < 2; jt++) {
            bf16x8 v;
            for (int e = 0; e < 8; e++) {
                int k = kt * 32 + kg * 8 + e;
                int j = jt * 16 + lo;
                v[e] = (__bf16)W0[(s * DIN + k) * DH1 + j];
            }
            *(bf16x8*)(fb + (kt * 2 + jt) * 1024 + l * 16) = v;
        }
    }
    for (int jt = 0; jt < 2; jt++) {
        bf16x8 v;
        for (int e = 0; e < 8; e++) {
            int k = kg * 8 + e;
            int j = jt * 16 + lo;
            v[e] = (__bf16)W1[(s * DH1 + k) * DH2 + j];
        }
        *(bf16x8*)(fb + 8192 + jt * 1024 + l * 16) = v;
    }
    for (int jt = 0; jt < 2; jt++) {
        *(float*)(fb + 10240 + (jt * 64 + l) * 4) = b0[s * DH1 + jt * 16 + lo];
        *(float*)(fb + 10752 + (jt * 64 + l) * 4) = b1[s * DH2 + jt * 16 + lo];
        *(float*)(fb + 11264 + (jt * 64 + l) * 4) = W2[s * DH2 + jt * 16 + lo];
    }
}

// ---------- K3: scatter atom indices into species segments ----------
__global__ void k3_scatter(const int* __restrict__ species, char* ws) {
    __shared__ int h[NSPEC];
    __shared__ int base[NSPEC];
    int t = threadIdx.x;
    if (t < NSPEC) h[t] = 0;
    __syncthreads();
    int i = blockIdx.x * blockDim.x + t;
    int s = 0, r = 0;
    bool ok = (i < NATOMS);
    if (ok) {
        s = species[i];
        r = atomicAdd(&h[s], 1);
    }
    __syncthreads();
    if (t < NSPEC) base[t] = atomicAdd((int*)(ws + OFF_CURS) + t, h[t]);
    __syncthreads();
    if (ok) ((int*)(ws + OFF_IDX))[base[s] + r] = i;
}

// ---------- K4: main MLP + reduce ----------
__global__ __launch_bounds__(256) void k4_main(const float* __restrict__ desc,
                                               const float* __restrict__ b2,
                                               const char* __restrict__ ws,
                                               float* __restrict__ out) {
    __shared__ alignas(16) __bf16 h1buf[4][16][32];

    const int* bases = (const int*)(ws + OFF_BASES);
    const int* idx   = (const int*)(ws + OFF_IDX);

    int tid = threadIdx.x;
    int l   = tid & 63;
    int w   = tid >> 6;
    int lo  = l & 15;
    int kg  = l >> 4;

    int gw = blockIdx.x * 4 + w;

    int B1 = bases[1], B2 = bases[2], B3 = bases[3];

    int scur = -1;
    bf16x8 w0f[4][2], w1f[2];
    float b0f[2], b1f[2], w2f[2], b2v = 0.0f;
    float esum = 0.0f;

    float4 dA[8], dB[8];

// idx fetch for strided tile j (masked OOB -> -1; pad slots hold -1 already)
#define IDX_LD(J_) ((gw + (J_) * K4_WAVES) < T_MAX ? idx[(gw + (J_) * K4_WAVES) * 16 + lo] : -1)

#define LOAD8(D_, IIV_) do {                                                  \
    int atom_ = (IIV_) < 0 ? 0 : (IIV_);                                      \
    const float* dp_ = desc + (size_t)atom_ * DIN + kg * 8;                   \
    D_[0] = *(const float4*)(dp_);       D_[1] = *(const float4*)(dp_ + 4);   \
    D_[2] = *(const float4*)(dp_ + 32);  D_[3] = *(const float4*)(dp_ + 36);  \
    D_[4] = *(const float4*)(dp_ + 64);  D_[5] = *(const float4*)(dp_ + 68);  \
    D_[6] = *(const float4*)(dp_ + 96);  D_[7] = *(const float4*)(dp_ + 100); \
} while (0)

#define COMPUTE(D_, IIV_, T_) do {                                            \
    int p0_ = (T_) * 16;                                                      \
    int s_ = (p0_ >= B3) ? 3 : (p0_ >= B2) ? 2 : (p0_ >= B1) ? 1 : 0;         \
    if (s_ != scur) {                                                         \
        const char* fb_ = ws + OFF_FRAG + (size_t)s_ * SPEC_STRIDE;           \
        _Pragma("unroll")                                                     \
        for (int kt = 0; kt < 4; kt++) {                                      \
            w0f[kt][0] = *(const bf16x8*)(fb_ + (kt * 2 + 0) * 1024 + l * 16);\
            w0f[kt][1] = *(const bf16x8*)(fb_ + (kt * 2 + 1) * 1024 + l * 16);\
        }                                                                     \
        w1f[0] = *(const bf16x8*)(fb_ + 8192 + l * 16);                       \
        w1f[1] = *(const bf16x8*)(fb_ + 8192 + 1024 + l * 16);                \
        b0f[0] = *(const float*)(fb_ + 10240 + l * 4);                        \
        b0f[1] = *(const float*)(fb_ + 10240 + (64 + l) * 4);                 \
        b1f[0] = *(const float*)(fb_ + 10752 + l * 4);                        \
        b1f[1] = *(const float*)(fb_ + 10752 + (64 + l) * 4);                 \
        w2f[0] = *(const float*)(fb_ + 11264 + l * 4);                        \
        w2f[1] = *(const float*)(fb_ + 11264 + (64 + l) * 4);                 \
        b2v = b2[s_];                                                         \
        scur = s_;                                                            \
    }                                                                         \
    f32x4 acc0_ = {0.f,0.f,0.f,0.f}, acc1_ = {0.f,0.f,0.f,0.f};               \
    _Pragma("unroll")                                                         \
    for (int kt = 0; kt < 4; kt++) {                                          \
        float4 x_ = D_[2 * kt], y_ = D_[2 * kt + 1];                          \
        bf16x8 a_;                                                            \
        a_[0] = (__bf16)x_.x; a_[1] = (__bf16)x_.y;                           \
        a_[2] = (__bf16)x_.z; a_[3] = (__bf16)x_.w;                           \
        a_[4] = (__bf16)y_.x; a_[5] = (__bf16)y_.y;                           \
        a_[6] = (__bf16)y_.z; a_[7] = (__bf16)y_.w;                           \
        acc0_ = __builtin_amdgcn_mfma_f32_16x16x32_bf16(a_, w0f[kt][0], acc0_, 0, 0, 0); \
        acc1_ = __builtin_amdgcn_mfma_f32_16x16x32_bf16(a_, w0f[kt][1], acc1_, 0, 0, 0); \
    }                                                                         \
    _Pragma("unroll")                                                         \
    for (int jt = 0; jt < 2; jt++) {                                          \
        float bb_ = b0f[jt];                                                  \
        _Pragma("unroll")                                                     \
        for (int r = 0; r < 4; r++) {                                         \
            float v_ = fast_tanh((jt ? acc1_[r] : acc0_[r]) + bb_);           \
            int roww_ = kg * 4 + r;                                           \
            int col_  = jt * 16 + lo;                                         \
            int sw_   = (col_ >> 3) ^ (roww_ & 3) ^ (roww_ >> 2);             \
            h1buf[w][roww_][sw_ * 8 + (col_ & 7)] = (__bf16)v_;               \
        }                                                                     \
    }                                                                         \
    int swr_ = kg ^ (lo & 3) ^ ((lo >> 2) & 3);                               \
    bf16x8 ha_ = *(bf16x8*)&h1buf[w][lo][swr_ * 8];                           \
    f32x4 c10_ = {0.f,0.f,0.f,0.f}, c11_ = {0.f,0.f,0.f,0.f};                 \
    c10_ = __builtin_amdgcn_mfma_f32_16x16x32_bf16(ha_, w1f[0], c10_, 0, 0, 0); \
    c11_ = __builtin_amdgcn_mfma_f32_16x16x32_bf16(ha_, w1f[1], c11_, 0, 0, 0); \
    unsigned long long bal_ = __ballot((IIV_) >= 0);                          \
    _Pragma("unroll")                                                         \
    for (int r = 0; r < 4; r++) {                                             \
        float h20_ = fast_tanh(c10_[r] + b1f[0]);                             \
        float h21_ = fast_tanh(c11_[r] + b1f[1]);                             \
        float pp_ = h20_ * w2f[0] + h21_ * w2f[1];                            \
        if ((bal_ >> (kg * 4 + r)) & 1ULL) esum += pp_;                       \
    }                                                                         \
    if (l == 0) esum += (float)__popcll(bal_ & 0xFFFFULL) * b2v;              \
} while (0)

    // pipeline prologue: idx two pairs ahead, desc one tile ahead
    int iiA  = IDX_LD(0);
    int iiB  = IDX_LD(1);
    int iiN0 = IDX_LD(2);
    int iiN1 = IDX_LD(3);
    LOAD8(dA, iiA);

    for (int j = 0; j < CHUNK - 1; j += 2) {
        LOAD8(dB, iiB);                                   // tile j+1 gather
        int nn0 = (j + 4 < CHUNK) ? IDX_LD(j + 4) : -1;   // idx two pairs out
        int nn1 = (j + 5 < CHUNK) ? IDX_LD(j + 5) : -1;
        COMPUTE(dA, iiA, gw + j * K4_WAVES);              // tile j
        LOAD8(dA, iiN0);                                  // tile j+2 gather
        COMPUTE(dB, iiB, gw + (j + 1) * K4_WAVES);        // tile j+1
        iiA = iiN0; iiB = iiN1; iiN0 = nn0; iiN1 = nn1;
    }
    COMPUTE(dA, iiA, gw + (CHUNK - 1) * K4_WAVES);        // tail tile (CHUNK odd)

    // single wave-wide reduction
    esum += __shfl_xor(esum, 1);
    esum += __shfl_xor(esum, 2);
    esum += __shfl_xor(esum, 4);
    esum += __shfl_xor(esum, 8);
    esum += __shfl_xor(esum, 16);
    esum += __shfl_xor(esum, 32);
    if (l == 0) atomicAdd(out, esum);

#undef IDX_LD
#undef LOAD8
#undef COMPUTE
}

extern "C" void kernel_launch(void* const* d_in, const int* in_sizes, int n_in,
                              void* d_out, int out_size, void* d_ws, size_t ws_size,
                              hipStream_t stream) {
    const float* desc    = (const float*)d_in[0];
    const int*   species = (const int*)d_in[1];
    const float* W0      = (const float*)d_in[2];
    const float* b0      = (const float*)d_in[3];
    const float* W1      = (const float*)d_in[4];
    const float* b1      = (const float*)d_in[5];
    const float* W2      = (const float*)d_in[6];
    const float* b2      = (const float*)d_in[7];
    char*  ws  = (char*)d_ws;
    float* out = (float*)d_out;

    int nb = (NATOMS + 1023) / 1024;   // 489

    k0_init<<<1, 64, 0, stream>>>(ws, out);
    k1_hist<<<nb, 1024, 0, stream>>>(species, ws);
    k2_prep<<<1, 256, 0, stream>>>(W0, b0, W1, b1, W2, ws);
    k3_scatter<<<nb, 1024, 0, stream>>>(species, ws);
    k4_main<<<K4_BLOCKS, 256, 0, stream>>>(desc, b2, ws, out);
}